// Round 1
// baseline (452.925 us; speedup 1.0000x reference)
//
#include <hip/hip_runtime.h>

// Problem constants (from reference): images (16,3,768,768) f32,
// h=w=48, N=2304, SIGMA_COLOR=0.1 -> exp(-50*cd), SIGMA_SPATIAL=5 -> exp(-0.02*sd), RADIUS=8.
#define BATCH 16
#define CH    3
#define HIN   768
#define WIN   768
#define HS    48
#define WS    48
#define NPIX  (HS * WS)          // 2304
#define PSZ   17                 // patch side = 2*RADIUS+1
#define QTOT  ((size_t)BATCH * NPIX * (NPIX / 4))   // float4 quads in out = 21,233,664

// Kernel 1: bilinear downsample 768->48 (half-pixel centers, scale 16).
// Output coord for index i is 16*i + 7.5 -> exact average of pixels {16i+7, 16i+8}
// in each axis, i.e. a 2x2 average. One thread per (b, n); writes float4 (c0,c1,c2,0).
__global__ void downsample_kernel(const float* __restrict__ img,
                                  float4* __restrict__ feats) {
    int idx = blockIdx.x * blockDim.x + threadIdx.x;   // over BATCH*NPIX = 36864
    if (idx >= BATCH * NPIX) return;
    int b = idx / NPIX;
    int n = idx - b * NPIX;
    int y = n / WS;
    int x = n - y * WS;
    int iy = 16 * y + 7;
    int ix = 16 * x + 7;
    const float* base = img + (size_t)b * CH * HIN * WIN;
    float f[3];
#pragma unroll
    for (int c = 0; c < 3; ++c) {
        const float* p = base + (size_t)c * HIN * WIN;
        const float* r0 = p + (size_t)iy * WIN + ix;
        const float* r1 = r0 + WIN;
        f[c] = 0.25f * (r0[0] + r0[1] + r1[0] + r1[1]);
    }
    feats[idx] = make_float4(f[0], f[1], f[2], 0.0f);
}

// Kernel 2: bulk zero fill of the whole output. 87.5% of the output is exact
// zeros (mask is a 17x17 patch per row); writing them through the compute
// kernel's divergent path was the bottleneck. The harness's own
// fillBufferAligned proves this buffer sustains ~6.36 TB/s with exactly this
// structure (256-thread blocks, dwordx4 stores).
__global__ __launch_bounds__(256) void fill_zero_kernel(float4* __restrict__ out) {
    size_t stride = (size_t)gridDim.x * blockDim.x;
    size_t t = (size_t)blockIdx.x * blockDim.x + threadIdx.x;
    const float4 z = make_float4(0.f, 0.f, 0.f, 0.f);
    for (size_t q = t; q < QTOT; q += stride) {
        out[q] = z;
    }
}

// Kernel 3: write only the non-zero 17x17 patch for each (b, i).
// One block per (b, i): 320 threads (5 waves), thread e < 289 handles patch
// element (r, c) = (e/17, e%17). By construction |dy|=|8-r|<=8 and
// |dx|=|8-c|<=8, so no mask test is needed -- only grid-border clipping.
// All of {b, i, yi, xi, fi} are block-uniform -> scalar; per-thread index
// math is one magic-div by 17.
__global__ __launch_bounds__(320) void patch_kernel(const float4* __restrict__ feats,
                                                    float* __restrict__ out) {
    int bi = blockIdx.x;              // b*NPIX + i, block-uniform
    int i  = bi % NPIX;
    int b  = bi / NPIX;
    int yi = i / WS;
    int xi = i - yi * WS;
    const float4* frow = feats + (size_t)b * NPIX;
    float4 fi = frow[i];              // broadcast load (same addr all lanes)

    int e = threadIdx.x;
    if (e >= PSZ * PSZ) return;
    int r = e / PSZ;
    int c = e - r * PSZ;
    int yj = yi - 8 + r;
    int xj = xi - 8 + c;
    if ((unsigned)yj < HS && (unsigned)xj < WS) {
        int j = yj * WS + xj;
        float4 fj = frow[j];
        float d0 = fi.x - fj.x;
        float d1 = fi.y - fj.y;
        float d2 = fi.z - fj.z;
        float cd = d0 * d0 + d1 * d1 + d2 * d2;
        int dy = 8 - r;
        int dx = 8 - c;
        float sd = (float)(dy * dy + dx * dx);
        out[(size_t)bi * NPIX + j] = __expf(-50.0f * cd - 0.02f * sd);
    }
}

extern "C" void kernel_launch(void* const* d_in, const int* in_sizes, int n_in,
                              void* d_out, int out_size, void* d_ws, size_t ws_size,
                              hipStream_t stream) {
    const float* img = (const float*)d_in[0];
    float4* feats = (float4*)d_ws;                 // needs 16*2304*16 B = 589,824 B
    float4* out4  = (float4*)d_out;                // 16*2304*2304 floats
    float*  out   = (float*)d_out;

    {
        // Bulk zero fill: grid-stride, 2048 blocks x 256 = 8 blocks/CU,
        // ~40 float4 stores per thread.
        int block = 256;
        int grid  = 2048;
        fill_zero_kernel<<<grid, block, 0, stream>>>(out4);
    }
    {
        int threads = BATCH * NPIX;                // 36,864
        int block = 256;
        int grid = (threads + block - 1) / block;  // 144
        downsample_kernel<<<grid, block, 0, stream>>>(img, feats);
    }
    {
        int grid = BATCH * NPIX;                   // 36,864 blocks, one per (b,i)
        int block = 320;                           // 5 waves; 289 active threads
        patch_kernel<<<grid, block, 0, stream>>>(feats, out);
    }
}

// Round 2
// 385.323 us; speedup vs baseline: 1.1754x; 1.1754x over previous
//
#include <hip/hip_runtime.h>

// Problem constants: images (16,3,768,768) f32, h=w=48, N=2304,
// SIGMA_COLOR=0.1 -> exp(-50*cd), SIGMA_SPATIAL=5 -> exp(-0.02*sd), RADIUS=8.
#define BATCH 16
#define CH    3
#define HIN   768
#define WIN   768
#define HS    48
#define WS    48
#define NPIX  (HS * WS)          // 2304
#define QPR   (NPIX / 4)         // 576 float4 quads per output row

// Kernel 1: bilinear downsample 768->48 (half-pixel centers, scale 16).
// Output coord for index i is 16*i + 7.5 -> exact average of pixels {16i+7, 16i+8}
// in each axis, i.e. a 2x2 average. One thread per (b, n); writes float4 (c0,c1,c2,0).
__global__ void downsample_kernel(const float* __restrict__ img,
                                  float4* __restrict__ feats) {
    int idx = blockIdx.x * blockDim.x + threadIdx.x;   // over BATCH*NPIX = 36864
    if (idx >= BATCH * NPIX) return;
    int b = idx / NPIX;
    int n = idx - b * NPIX;
    int y = n / WS;
    int x = n - y * WS;
    int iy = 16 * y + 7;
    int ix = 16 * x + 7;
    const float* base = img + (size_t)b * CH * HIN * WIN;
    float f[3];
#pragma unroll
    for (int c = 0; c < 3; ++c) {
        const float* p = base + (size_t)c * HIN * WIN;
        const float* r0 = p + (size_t)iy * WIN + ix;
        const float* r1 = r0 + WIN;
        f[c] = 0.25f * (r0[0] + r0[1] + r1[0] + r1[1]);
    }
    feats[idx] = make_float4(f[0], f[1], f[2], 0.0f);
}

// Kernel 2 (fused): one block per output row (b, i). Block = (12, 48) = 576
// threads = 9 waves; thread (xq, yj) owns the float4 quad at j-row yj,
// columns 4*xq..4*xq+3. Flat lane id = xq + 12*yj, so the block's stores are
// one contiguous 9216-B span -- full cache lines, written exactly once, no
// read-for-ownership, no second pass.
//
// Why this beats both prior versions:
//  - (b, i) live in blockIdx -> i-decode (yi, xi) and the fi load are
//    scalar/SALU + s_load; ZERO per-thread integer divisions anywhere
//    (round-0 kernel spent a magic-mul chain per thread on t%576, /576,
//    %2304, /2304).
//  - (yj, xq) come straight from threadIdx -> dy test needs one SALU-vs-VALU
//    sub; ~54% of waves are all-|dy|>8 and do nothing but a zero store.
//  - zeros and values land in the same full-line store (round-1's split
//    passes touched the output twice and did partial-line RFO writes).
__global__ __launch_bounds__(576) void row_affinity_kernel(const float4* __restrict__ feats,
                                                           float4* __restrict__ out) {
    int i = blockIdx.x;               // 0..2303, block-uniform
    int b = blockIdx.y;               // 0..15
    int yi = i / WS;                  // SALU (blockIdx-derived)
    int xi = i - yi * WS;
    const float4* frow = feats + (size_t)b * NPIX;

    int xq = threadIdx.x;             // 0..11  (quad within j-row)
    int yj = threadIdx.y;             // 0..47  (j-row)
    int dy = yi - yj;

    float4 res;
    if (dy > 8 || dy < -8) {
        res = make_float4(0.f, 0.f, 0.f, 0.f);
    } else {
        float4 fi = frow[i];          // wave-uniform address
        float sdy = (float)(dy * dy);
        int xj0 = xq * 4;
        int j0  = yj * WS + xj0;
        float v[4];
#pragma unroll
        for (int k = 0; k < 4; ++k) {
            int dx = xi - (xj0 + k);
            float4 fj = frow[j0 + k];
            float d0 = fi.x - fj.x;
            float d1 = fi.y - fj.y;
            float d2 = fi.z - fj.z;
            float cd = d0 * d0 + d1 * d1 + d2 * d2;
            float sd = sdy + (float)(dx * dx);
            float e  = __expf(-50.0f * cd - 0.02f * sd);
            v[k] = (dx > 8 || dx < -8) ? 0.0f : e;
        }
        res = make_float4(v[0], v[1], v[2], v[3]);
    }
    // row base: (b*NPIX + i) * 576 quads; lane offset yj*12 + xq
    out[(size_t)(b * NPIX + i) * QPR + yj * 12 + xq] = res;
}

extern "C" void kernel_launch(void* const* d_in, const int* in_sizes, int n_in,
                              void* d_out, int out_size, void* d_ws, size_t ws_size,
                              hipStream_t stream) {
    const float* img = (const float*)d_in[0];
    float4* feats = (float4*)d_ws;                 // 16*2304*16 B = 589,824 B
    float4* out4  = (float4*)d_out;                // 16*2304*2304 floats

    {
        int threads = BATCH * NPIX;                // 36,864
        int block = 256;
        int grid = (threads + block - 1) / block;  // 144
        downsample_kernel<<<grid, block, 0, stream>>>(img, feats);
    }
    {
        dim3 grid(NPIX, BATCH);                    // 2304 x 16 blocks, one per row
        dim3 block(12, 48);                        // 576 threads = 9 waves
        row_affinity_kernel<<<grid, block, 0, stream>>>(feats, out4);
    }
}